// Round 7
// baseline (67.579 us; speedup 1.0000x reference)
//
#include <hip/hip_runtime.h>

// KNNInteractionGraph — fused row-per-wave kernel, fat workgroups.
// N=8192, K=32, CUTOFF=10, batch sorted (molecules contiguous, n ~ 64+-8).
//
// Round-7 change: 1024-thread blocks (16 waves), grid 512 WGs (was 2048) to
// amortize workgroup launch/drain; __launch_bounds__(1024,4) -> <=128 VGPR,
// no spill risk. Per-wave algorithm identical to round 6 (absmax was 0):
//   - molecule range via ballot window-scan over batch (2 coalesced loads)
//   - lane owns column c = 64j+lane, distance in registers
//   - stable rank (value asc, index asc) via v_readlane broadcast sweep
//
// Output (float32, 3*N*K): [indices | centers | weights].

#define CUTOFF_F 10.0f
#define ROWS_PER_BLOCK 16
#define BLOCK_THREADS 1024

__device__ __forceinline__ float readlane_f(float v, int lane) {
    return __int_as_float(__builtin_amdgcn_readlane(__float_as_int(v), lane));
}
__device__ __forceinline__ int readlane_i(int v, int lane) {
    return __builtin_amdgcn_readlane(v, lane);
}

// Reference-exact masked distance (gram expansion, f32, no FMA contraction):
__device__ __forceinline__ float dist_v(float4 pr, float4 pc, bool diag) {
    if (diag) return CUTOFF_F;
    float dot = __fadd_rn(__fadd_rn(__fmul_rn(pr.x, pc.x), __fmul_rn(pr.y, pc.y)),
                          __fmul_rn(pr.z, pc.z));
    float sq = __fsub_rn(__fadd_rn(pr.w, pc.w), __fadd_rn(dot, dot));
    sq = fmaxf(sq, 0.0f);
    float d = (sq > 0.0f) ? __fsqrt_rn(sq) : 0.0f;
    return (d > CUTOFF_F) ? CUTOFF_F : d;
}

__device__ __forceinline__ float4 load_pos4(const float* __restrict__ pos, int g) {
    float x = pos[g * 3 + 0];
    float y = pos[g * 3 + 1];
    float z = pos[g * 3 + 2];
    float sq = __fadd_rn(__fadd_rn(__fmul_rn(x, x), __fmul_rn(y, y)), __fmul_rn(z, z));
    return make_float4(x, y, z, sq);
}

// ---------------- hot row core: columns in registers, n <= 64*NCH -------------
template <int NCH>
__device__ __forceinline__ void row_core_reg(const float* __restrict__ pos,
                                             float4 pr, int n, int lane,
                                             int start, int end, int r,
                                             float* __restrict__ out,
                                             int NK, int K) {
    float v[NCH];
    int   rk[NCH];
#pragma unroll
    for (int j = 0; j < NCH; ++j) {
        const int c = 64 * j + lane;
        v[j]  = (c < n) ? dist_v(pr, load_pos4(pos, start + c), (start + c) == r)
                        : CUTOFF_F;
        rk[j] = 0;
    }
    // stable rank sweep: broadcast column g's value (uniform lane index)
#pragma unroll
    for (int jj = 0; jj < NCH; ++jj) {
        const int base = 64 * jj;
        const int lim  = (NCH == 1) ? n : min(n - base, 64);
#pragma unroll 4
        for (int cc = 0; cc < lim; ++cc) {
            const float vv = readlane_f(v[jj], cc);
            const int   g  = base + cc;
#pragma unroll
            for (int j = 0; j < NCH; ++j) {
                const int c = 64 * j + lane;
                rk[j] += (vv < v[j]) || (vv == v[j] && g < c);  // (value asc, idx asc)
            }
        }
    }
    int m = 0;
#pragma unroll
    for (int j = 0; j < NCH; ++j) {
        const int c = 64 * j + lane;
        m += __popcll(__ballot(c < n && v[j] < CUTOFF_F));
    }
#pragma unroll
    for (int j = 0; j < NCH; ++j) {
        const int c = 64 * j + lane;
        if (c < n && v[j] < CUTOFF_F && rk[j] < K) {
            const int o = r * K + rk[j];
            out[o]          = (float)(start + c);
            out[2 * NK + o] = v[j];
        }
    }
    for (int k2 = lane; k2 < K; k2 += 64)     // centers chunk
        out[NK + r * K + k2] = (float)r;
    // fill slots [m,K): CUTOFF at globally-smallest masked indices
    // {0..start-1} U {in-mol masked} U {end..N-1}  (lax.top_k tie order).
    if (m < K) {
        const int mm = n - m;                 // in-mol masked count (incl diag)
        for (int fb = 0; fb < K - m; fb += 64) {
            const int t = fb + lane;
            const bool active = t < (K - m);
            int idx = 0;
            bool found = false;
            if (active) {
                if (t < start)            { idx = t;                      found = true; }
                else if (t - start >= mm) { idx = end + (t - start - mm); found = true; }
            }
            if (__any(active && !found)) {
                int cnt = 0;
#pragma unroll
                for (int jj = 0; jj < NCH; ++jj) {
                    const int base = 64 * jj;
                    const int lim  = min(n - base, 64);
                    for (int cc = 0; cc < lim; ++cc) {
                        if (readlane_f(v[jj], cc) == CUTOFF_F) {
                            if (active && !found && cnt == t - start) {
                                idx = start + base + cc; found = true;
                            }
                            ++cnt;
                        }
                    }
                }
            }
            if (active) {
                const int o = r * K + m + t;
                out[o]          = (float)idx;
                out[2 * NK + o] = CUTOFF_F;
            }
        }
    }
}

// ------------- cold paths: own register allocation (noinline) -----------------
__device__ __attribute__((noinline))
int lower_bound_cold(const int* __restrict__ batch, int lo, int hi, int key) {
    while (lo < hi) {
        int mid = (lo + hi) >> 1;
        if (batch[mid] < key) lo = mid + 1; else hi = mid;
    }
    return lo;
}

__device__ __attribute__((noinline))
void row_core_fallback(const float* __restrict__ pos, float4 pr, int n, int lane,
                       int start, int end, int r, float* __restrict__ out,
                       int NK, int K) {
    // generic global-recompute path, correct for any n (never taken here)
    int m = 0;
    for (int cb = 0; cb < n; cb += 64) {
        const int c = cb + lane;
        const float v = (c < n)
            ? dist_v(pr, load_pos4(pos, start + c), (start + c) == r) : CUTOFF_F;
        int rk = 0;
        for (int cc = 0; cc < n; ++cc) {
            const float vv = dist_v(pr, load_pos4(pos, start + cc), (start + cc) == r);
            rk += (vv < v) || (vv == v && cc < c);
        }
        if (c < n && v < CUTOFF_F && rk < K) {
            const int o = r * K + rk;
            out[o]          = (float)(start + c);
            out[2 * NK + o] = v;
        }
        m += __popcll(__ballot(c < n && v < CUTOFF_F));
    }
    for (int k2 = lane; k2 < K; k2 += 64)
        out[NK + r * K + k2] = (float)r;
    if (m < K) {
        const int mm = n - m;
        for (int fb = 0; fb < K - m; fb += 64) {
            const int t = fb + lane;
            const bool active = t < (K - m);
            int idx = 0; bool found = false;
            if (active) {
                if (t < start)            { idx = t;                      found = true; }
                else if (t - start >= mm) { idx = end + (t - start - mm); found = true; }
            }
            if (__any(active && !found)) {
                int cnt = 0;
                for (int cc = 0; cc < n; ++cc) {
                    if (dist_v(pr, load_pos4(pos, start + cc), (start + cc) == r)
                        == CUTOFF_F) {
                        if (active && !found && cnt == t - start) {
                            idx = start + cc; found = true;
                        }
                        ++cnt;
                    }
                }
            }
            if (active) {
                const int o = r * K + m + t;
                out[o]          = (float)idx;
                out[2 * NK + o] = CUTOFF_F;
            }
        }
    }
}

// ---------------- kernel ------------------------------------------------------
__global__ __launch_bounds__(BLOCK_THREADS, 4)
void knn_fused_kernel(const float* __restrict__ pos,
                      const int* __restrict__ batch,
                      float* __restrict__ out,
                      int N, int K) {
    const int w    = threadIdx.x >> 6;
    const int lane = threadIdx.x & 63;
    const int r    = blockIdx.x * ROWS_PER_BLOCK + w;
    if (r >= N) return;                       // no LDS, no barriers
    const int NK = N * K;

    // issue all independent loads up front (chain depth 1)
    const int iu = r - 63 + lane;             // upward window: idx r-63 .. r
    const int id = r + 1 + lane;              // downward window: idx r+1 .. r+64
    const int au = batch[max(iu, 0)];
    const int ad = batch[min(id, N - 1)];
    const float4 pr = load_pos4(pos, r);

    const int b = readlane_i(au, 63);         // batch[r]

    // start: leading-ones run of the upward match mask
    const unsigned long long mu = __ballot(iu >= 0 && au == b);   // bit63 always set
    int start;
    if (mu != ~0ull) {
        start = r - __builtin_clzll(~mu) + 1;
    } else {
        const int iu2 = r - 127 + lane;
        const unsigned long long mu2 =
            __ballot(iu2 >= 0 && batch[max(iu2, 0)] == b);
        if (mu2 != ~0ull)           start = r - 63 - __builtin_clzll(~mu2);
        else if (r - 127 <= 0)      start = 0;
        else                        start = lower_bound_cold(batch, 0, r, b);
    }

    // end: trailing-ones run of the downward match mask
    const unsigned long long md = __ballot(id < N && ad == b);
    int end;
    if (md != ~0ull) {
        end = r + 1 + __builtin_ctzll(~md);
    } else {
        const int id2 = r + 65 + lane;
        const unsigned long long md2 =
            __ballot(id2 < N && batch[min(id2, N - 1)] == b);
        if (md2 != ~0ull)           end = r + 65 + __builtin_ctzll(~md2);
        else if (r + 129 >= N)      end = N;
        else                        end = lower_bound_cold(batch, r + 1, N, b + 1);
    }

    const int n = end - start;

    if      (n <= 64)  row_core_reg<1>(pos, pr, n, lane, start, end, r, out, NK, K);
    else if (n <= 128) row_core_reg<2>(pos, pr, n, lane, start, end, r, out, NK, K);
    else               row_core_fallback(pos, pr, n, lane, start, end, r, out, NK, K);
}

extern "C" void kernel_launch(void* const* d_in, const int* in_sizes, int n_in,
                              void* d_out, int out_size, void* d_ws, size_t ws_size,
                              hipStream_t stream) {
    const float* pos   = (const float*)d_in[0];   // [N,3] float32
    const int*   batch = (const int*)d_in[1];     // [N]   int32, sorted
    float*       out   = (float*)d_out;           // float32, 3*N*K

    const int N = in_sizes[1];            // 8192
    const int K = out_size / (3 * N);     // 32

    const int grid = (N + ROWS_PER_BLOCK - 1) / ROWS_PER_BLOCK;  // 512
    knn_fused_kernel<<<grid, BLOCK_THREADS, 0, stream>>>(pos, batch, out, N, K);
}

// Round 8
// 64.958 us; speedup vs baseline: 1.0403x; 1.0403x over previous
//
#include <hip/hip_runtime.h>

// KNNInteractionGraph — row-per-wave, cross-lane bitonic-sort selection.
// N=8192, K=32, CUTOFF=10, batch sorted (molecules contiguous, n ~ 64+-8).
//
// Round-8 change: replace the O(n) readlane rank sweep (~64-90 serial
// iterations/wave) with a bitonic sort of packed u64 keys (v_bits<<32 | col):
// 21 shfl_xor stages for n<=64, 28 for n<=128. Keys unique -> total order ==
// stable (value asc, index asc) == lax.top_k tie order. Sorted lane L writes
// output slot L directly (coalesced).
//
// Output (float32, 3*N*K): [indices | centers | weights].

#define CUTOFF_F 10.0f
#define ROWS_PER_BLOCK 4

__device__ __forceinline__ float readlane_f(float v, int lane) {
    return __int_as_float(__builtin_amdgcn_readlane(__float_as_int(v), lane));
}
__device__ __forceinline__ int readlane_i(int v, int lane) {
    return __builtin_amdgcn_readlane(v, lane);
}
__device__ __forceinline__ unsigned long long shfl_xor_u64(unsigned long long x, int m) {
    const int lo = __shfl_xor((int)(unsigned)(x & 0xffffffffull), m, 64);
    const int hi = __shfl_xor((int)(unsigned)(x >> 32), m, 64);
    return ((unsigned long long)(unsigned)hi << 32) | (unsigned)lo;
}

// Reference-exact masked distance (gram expansion, f32, no FMA contraction):
__device__ __forceinline__ float dist_v(float4 pr, float4 pc, bool diag) {
    if (diag) return CUTOFF_F;
    float dot = __fadd_rn(__fadd_rn(__fmul_rn(pr.x, pc.x), __fmul_rn(pr.y, pc.y)),
                          __fmul_rn(pr.z, pc.z));
    float sq = __fsub_rn(__fadd_rn(pr.w, pc.w), __fadd_rn(dot, dot));
    sq = fmaxf(sq, 0.0f);
    float d = (sq > 0.0f) ? __fsqrt_rn(sq) : 0.0f;
    return (d > CUTOFF_F) ? CUTOFF_F : d;
}

__device__ __forceinline__ float4 load_pos4(const float* __restrict__ pos, int g) {
    float x = pos[g * 3 + 0];
    float y = pos[g * 3 + 1];
    float z = pos[g * 3 + 2];
    float sq = __fadd_rn(__fadd_rn(__fmul_rn(x, x), __fmul_rn(y, y)), __fmul_rn(z, z));
    return make_float4(x, y, z, sq);
}

// Keys: (f32_bits(v) << 32) | col. v >= 0 so float-bit order == value order;
// col unique -> total order == (v asc, col asc).
__device__ __forceinline__ unsigned long long pack_key(float v, int c) {
    return ((unsigned long long)(unsigned)__float_as_int(v) << 32) | (unsigned)c;
}

// Ascending bitonic sort of 64 keys, one per lane.
__device__ __forceinline__ unsigned long long bitonic64(unsigned long long key, int lane) {
#pragma unroll
    for (int k = 2; k <= 64; k <<= 1) {
#pragma unroll
        for (int j = k >> 1; j > 0; j >>= 1) {
            const unsigned long long pk = shfl_xor_u64(key, j);
            const bool take_min = (((lane & j) == 0) == ((lane & k) == 0));
            key = ((pk < key) == take_min) ? pk : key;
        }
    }
    return key;
}

// Ascending bitonic sort of 128 keys, two per lane (A: vpos=lane, B: vpos=64+lane).
__device__ __forceinline__ void bitonic128(unsigned long long& ka,
                                           unsigned long long& kb, int lane) {
#pragma unroll
    for (int k = 2; k <= 128; k <<= 1) {
#pragma unroll
        for (int j = k >> 1; j > 0; j >>= 1) {
            if (j == 64) {            // only in the final k=128 merge: in-lane A<->B
                const bool alt = ka < kb;
                const unsigned long long mn = alt ? ka : kb;
                const unsigned long long mx = alt ? kb : ka;
                ka = mn; kb = mx;     // A (vpos<64) keeps min, ascending merge
            } else {
                const unsigned long long pa = shfl_xor_u64(ka, j);
                const unsigned long long pb = shfl_xor_u64(kb, j);
                const bool low = ((lane & j) == 0);
                const bool upA = ((lane & k) == 0);          // A: vpos=lane (<64)
                const bool upB = (k == 64) ? false : upA;    // B: vpos=64+lane
                ka = ((pa < ka) == (low == upA)) ? pa : ka;
                kb = ((pb < kb) == (low == upB)) ? pb : kb;
            }
        }
    }
}

// Cold fill: slots [m,K) get CUTOFF at globally-smallest masked indices:
// {0..start-1} U {in-mol masked (v==CUTOFF)} U {end..N-1} (lax.top_k tie order).
template <int NCH>
__device__ __forceinline__ void do_fill(const float* v, int m, int K, int lane,
                                        int start, int end, int n, int r, int NK,
                                        float* __restrict__ out) {
    const int mm = n - m;             // in-mol masked count (incl diagonal)
    for (int fb = 0; fb < K - m; fb += 64) {
        const int t = fb + lane;
        const bool active = t < (K - m);
        int idx = 0;
        bool found = false;
        if (active) {
            if (t < start)            { idx = t;                      found = true; }
            else if (t - start >= mm) { idx = end + (t - start - mm); found = true; }
        }
        if (__any(active && !found)) {
            int cnt = 0;
#pragma unroll
            for (int jj = 0; jj < NCH; ++jj) {
                const int base = 64 * jj;
                const int lim  = min(n - base, 64);
                for (int cc = 0; cc < lim; ++cc) {
                    if (readlane_f(v[jj], cc) == CUTOFF_F) {
                        if (active && !found && cnt == t - start) {
                            idx = start + base + cc; found = true;
                        }
                        ++cnt;
                    }
                }
            }
        }
        if (active) {
            const int o = r * K + m + t;
            out[o]          = (float)idx;
            out[2 * NK + o] = CUTOFF_F;
        }
    }
}

// ---------------- hot cores: bitonic selection --------------------------------
__device__ __forceinline__ void row_core_sort64(const float* __restrict__ pos,
                                                float4 pr, int n, int lane,
                                                int start, int end, int r,
                                                float* __restrict__ out,
                                                int NK, int K) {
    const int c = lane;
    float v[1];
    v[0] = (c < n) ? dist_v(pr, load_pos4(pos, start + c), (start + c) == r)
                   : CUTOFF_F;
    unsigned long long key = pack_key(v[0], c);
    key = bitonic64(key, lane);

    const float vs = __int_as_float((int)(unsigned)(key >> 32));
    const int   cs = (int)(unsigned)(key & 0xffffffffull);
    if (lane < K && vs < CUTOFF_F) {              // sorted slot L = lane (coalesced)
        const int o = r * K + lane;
        out[o]          = (float)(start + cs);
        out[2 * NK + o] = vs;
    }
    for (int k2 = lane; k2 < K; k2 += 64)         // centers chunk
        out[NK + r * K + k2] = (float)r;
    const int m = __popcll(__ballot(v[0] < CUTOFF_F));
    if (m < K) do_fill<1>(v, m, K, lane, start, end, n, r, NK, out);
}

__device__ __forceinline__ void row_core_sort128(const float* __restrict__ pos,
                                                 float4 pr, int n, int lane,
                                                 int start, int end, int r,
                                                 float* __restrict__ out,
                                                 int NK, int K) {
    const int cA = lane, cB = 64 + lane;
    float v[2];
    v[0] = (cA < n) ? dist_v(pr, load_pos4(pos, start + cA), (start + cA) == r)
                    : CUTOFF_F;
    v[1] = (cB < n) ? dist_v(pr, load_pos4(pos, start + cB), (start + cB) == r)
                    : CUTOFF_F;
    unsigned long long ka = pack_key(v[0], cA);
    unsigned long long kb = pack_key(v[1], cB);
    bitonic128(ka, kb, lane);

    const float vsa = __int_as_float((int)(unsigned)(ka >> 32));
    const int   csa = (int)(unsigned)(ka & 0xffffffffull);
    if (lane < K && vsa < CUTOFF_F) {             // sorted slots 0..63 from A
        const int o = r * K + lane;
        out[o]          = (float)(start + csa);
        out[2 * NK + o] = vsa;
    }
    if (64 + lane < K) {                          // K<=64 in practice: cold
        const float vsb = __int_as_float((int)(unsigned)(kb >> 32));
        const int   csb = (int)(unsigned)(kb & 0xffffffffull);
        if (vsb < CUTOFF_F) {
            const int o = r * K + 64 + lane;
            out[o]          = (float)(start + csb);
            out[2 * NK + o] = vsb;
        }
    }
    for (int k2 = lane; k2 < K; k2 += 64)         // centers chunk
        out[NK + r * K + k2] = (float)r;
    const int m = __popcll(__ballot(v[0] < CUTOFF_F))
                + __popcll(__ballot(v[1] < CUTOFF_F));
    if (m < K) do_fill<2>(v, m, K, lane, start, end, n, r, NK, out);
}

// ------------- cold paths: own register allocation (noinline) -----------------
__device__ __attribute__((noinline))
int lower_bound_cold(const int* __restrict__ batch, int lo, int hi, int key) {
    while (lo < hi) {
        int mid = (lo + hi) >> 1;
        if (batch[mid] < key) lo = mid + 1; else hi = mid;
    }
    return lo;
}

__device__ __attribute__((noinline))
void row_core_fallback(const float* __restrict__ pos, float4 pr, int n, int lane,
                       int start, int end, int r, float* __restrict__ out,
                       int NK, int K) {
    // generic global-recompute path, correct for any n (never taken here)
    int m = 0;
    for (int cb = 0; cb < n; cb += 64) {
        const int c = cb + lane;
        const float v = (c < n)
            ? dist_v(pr, load_pos4(pos, start + c), (start + c) == r) : CUTOFF_F;
        int rk = 0;
        for (int cc = 0; cc < n; ++cc) {
            const float vv = dist_v(pr, load_pos4(pos, start + cc), (start + cc) == r);
            rk += (vv < v) || (vv == v && cc < c);
        }
        if (c < n && v < CUTOFF_F && rk < K) {
            const int o = r * K + rk;
            out[o]          = (float)(start + c);
            out[2 * NK + o] = v;
        }
        m += __popcll(__ballot(c < n && v < CUTOFF_F));
    }
    for (int k2 = lane; k2 < K; k2 += 64)
        out[NK + r * K + k2] = (float)r;
    if (m < K) {
        const int mm = n - m;
        for (int fb = 0; fb < K - m; fb += 64) {
            const int t = fb + lane;
            const bool active = t < (K - m);
            int idx = 0; bool found = false;
            if (active) {
                if (t < start)            { idx = t;                      found = true; }
                else if (t - start >= mm) { idx = end + (t - start - mm); found = true; }
            }
            if (__any(active && !found)) {
                int cnt = 0;
                for (int cc = 0; cc < n; ++cc) {
                    if (dist_v(pr, load_pos4(pos, start + cc), (start + cc) == r)
                        == CUTOFF_F) {
                        if (active && !found && cnt == t - start) {
                            idx = start + cc; found = true;
                        }
                        ++cnt;
                    }
                }
            }
            if (active) {
                const int o = r * K + m + t;
                out[o]          = (float)idx;
                out[2 * NK + o] = CUTOFF_F;
            }
        }
    }
}

// ---------------- kernel ------------------------------------------------------
__global__ __launch_bounds__(256, 8)
void knn_fused_kernel(const float* __restrict__ pos,
                      const int* __restrict__ batch,
                      float* __restrict__ out,
                      int N, int K) {
    const int w    = threadIdx.x >> 6;
    const int lane = threadIdx.x & 63;
    const int r    = blockIdx.x * ROWS_PER_BLOCK + w;
    if (r >= N) return;                       // no LDS, no barriers
    const int NK = N * K;

    // issue all independent loads up front (chain depth 1)
    const int iu = r - 63 + lane;             // upward window: idx r-63 .. r
    const int id = r + 1 + lane;              // downward window: idx r+1 .. r+64
    const int au = batch[max(iu, 0)];
    const int ad = batch[min(id, N - 1)];
    const float4 pr = load_pos4(pos, r);

    const int b = readlane_i(au, 63);         // batch[r]

    // start: leading-ones run of the upward match mask
    const unsigned long long mu = __ballot(iu >= 0 && au == b);   // bit63 always set
    int start;
    if (mu != ~0ull) {
        start = r - __builtin_clzll(~mu) + 1;
    } else {
        const int iu2 = r - 127 + lane;
        const unsigned long long mu2 =
            __ballot(iu2 >= 0 && batch[max(iu2, 0)] == b);
        if (mu2 != ~0ull)           start = r - 63 - __builtin_clzll(~mu2);
        else if (r - 127 <= 0)      start = 0;
        else                        start = lower_bound_cold(batch, 0, r, b);
    }

    // end: trailing-ones run of the downward match mask
    const unsigned long long md = __ballot(id < N && ad == b);
    int end;
    if (md != ~0ull) {
        end = r + 1 + __builtin_ctzll(~md);
    } else {
        const int id2 = r + 65 + lane;
        const unsigned long long md2 =
            __ballot(id2 < N && batch[min(id2, N - 1)] == b);
        if (md2 != ~0ull)           end = r + 65 + __builtin_ctzll(~md2);
        else if (r + 129 >= N)      end = N;
        else                        end = lower_bound_cold(batch, r + 1, N, b + 1);
    }

    const int n = end - start;

    if      (n <= 64)  row_core_sort64 (pos, pr, n, lane, start, end, r, out, NK, K);
    else if (n <= 128) row_core_sort128(pos, pr, n, lane, start, end, r, out, NK, K);
    else               row_core_fallback(pos, pr, n, lane, start, end, r, out, NK, K);
}

extern "C" void kernel_launch(void* const* d_in, const int* in_sizes, int n_in,
                              void* d_out, int out_size, void* d_ws, size_t ws_size,
                              hipStream_t stream) {
    const float* pos   = (const float*)d_in[0];   // [N,3] float32
    const int*   batch = (const int*)d_in[1];     // [N]   int32, sorted
    float*       out   = (float*)d_out;           // float32, 3*N*K

    const int N = in_sizes[1];            // 8192
    const int K = out_size / (3 * N);     // 32

    const int grid = (N + ROWS_PER_BLOCK - 1) / ROWS_PER_BLOCK;  // 2048
    knn_fused_kernel<<<grid, 256, 0, stream>>>(pos, batch, out, N, K);
}